// Round 1
// 113.598 us; speedup vs baseline: 1.0414x; 1.0414x over previous
//
#include <hip/hip_runtime.h>
#include <stdint.h>

#define LL 256
#define DD 256
#define CH 32

typedef __attribute__((ext_vector_type(2))) _Float16 f16x2;
typedef __attribute__((ext_vector_type(8))) _Float16 halfx8;
typedef __attribute__((ext_vector_type(4))) float f32x4;

static __device__ __forceinline__ uint32_t pk16(float a, float b) {
  f16x2 p; p.x = (_Float16)a; p.y = (_Float16)b;   // RTN casts
  return __builtin_bit_cast(uint32_t, p);
}
static __device__ __forceinline__ f16x2 bc2(uint32_t u) { return __builtin_bit_cast(f16x2, u); }
static __device__ __forceinline__ halfx8 bc8(uint4 u) { return __builtin_bit_cast(halfx8, u); }

// ---------------------------------------------------------------------------
// Kernel P: one-time packing.
//  blocks [0,256):   x fp32 -> xf f16 (8 elems/thread, coalesced float4 loads)
//  blocks [256,320): W1 -> w1p f16 in MFMA-A-frag layout with the d-permutation
//  block 320:        W2 -> w2p packed f16 pairs
// ---------------------------------------------------------------------------
__global__ void bepler_pack(const float* __restrict__ x, const float* __restrict__ W1,
                            const float* __restrict__ W2, _Float16* __restrict__ xf,
                            _Float16* __restrict__ w1p, uint32_t* __restrict__ w2p) {
  const int gid = blockIdx.x * 256 + threadIdx.x;
  if (blockIdx.x < 256) {
    const float4 f0 = ((const float4*)x)[gid * 2];
    const float4 f1 = ((const float4*)x)[gid * 2 + 1];
    uint4 v;
    v.x = pk16(f0.x, f0.y); v.y = pk16(f0.z, f0.w);
    v.z = pk16(f1.x, f1.y); v.w = pk16(f1.z, f1.w);
    ((uint4*)xf)[gid] = v;
  } else if (blockIdx.x < 320) {
    const int idx = gid - 65536;           // 0..16383
    const int t  = idx & 7;
    const int l  = (idx >> 3) & 63;
    const int hM = (idx >> 9) & 1;
    const int s  = idx >> 10;
    const int g  = (l >> 4) & 3;
    const int d  = 32 * (s >> 1) + 8 * g + 4 * (s & 1) + 2 * ((t >> 2) & 1) + (t & 1);
    const int ko = (t & 2) ? (DD + d) : d;
    w1p[idx] = (_Float16)W1[ko * CH + 16 * hM + (l & 15)];
  } else {
    for (int k = threadIdx.x; k < 784; k += 256) {
      const int t  = k & 3;
      const int dj = (k >> 2) % 7;
      const int qd = (k >> 2) / 7;         // di*4+q
      const int q  = qd & 3;
      const int di = qd >> 2;
      const int c  = q * 8 + 2 * t;
      w2p[k] = pk16(W2[(di * 7 + dj) * 32 + c], W2[(di * 7 + dj) * 32 + c + 1]);
    }
  }
}

// ---------------------------------------------------------------------------
// Kernel A: h[b,i,j,c] = mask * relu( z . W1[:,c] + b1[c] ), f16 out.
// NEW: blocks entirely beyond protein_length[b] exit immediately (no compute,
// no stores). Kernel B never reads hws at gi>=len or gj>=len, so the skipped
// (poisoned) region is never observed.
// ---------------------------------------------------------------------------
#define XPAD 272
__global__ __launch_bounds__(256, 2) void bepler_h_kernel(
    const _Float16* __restrict__ xf, const int* __restrict__ plen,
    const uint4* __restrict__ w1p4, const float* __restrict__ b1,
    _Float16* __restrict__ hws)
{
  __shared__ _Float16 xi[32 * XPAD];   // 17.4 KB
  __shared__ _Float16 xj[32 * XPAD];

  const int tid  = threadIdx.x;
  const int lane = tid & 63;
  const int wave = tid >> 6;
  const int b  = blockIdx.z;
  const int i0 = blockIdx.y * 32;
  const int j0 = blockIdx.x * 32;

  const int len = plen[b];
  if (i0 >= len || j0 >= len) return;   // block-uniform: whole tile is masked out

  const int g   = lane >> 4;
  const int m16 = lane & 15;

  // Load all 32 A-fragments from prepacked global (coalesced, L2-hot): 128 VGPR
  uint4 af[16][2];
#pragma unroll
  for (int s = 0; s < 16; ++s) {
#pragma unroll
    for (int hM = 0; hM < 2; ++hM)
      af[s][hM] = w1p4[(s * 2 + hM) * 64 + lane];
  }

  // Stage x tiles (pure uint4 copies from pre-converted xf)
  const _Float16* xfb = xf + (size_t)b * LL * DD;
  for (int idx = tid; idx < 1024; idx += 256) {
    const int r = idx >> 5, cg = idx & 31;
    ((uint4*)(xi + r * XPAD))[cg] = ((const uint4*)(xfb + (i0 + r) * DD))[cg];
    ((uint4*)(xj + r * XPAD))[cg] = ((const uint4*)(xfb + (j0 + r) * DD))[cg];
  }

  float b1v[2][4];
#pragma unroll
  for (int r = 0; r < 4; ++r) {
    b1v[0][r] = b1[g * 4 + r];
    b1v[1][r] = b1[16 + g * 4 + r];
  }
  __syncthreads();

  for (int ip = 0; ip < 4; ++ip) {       // i-row pairs
    const int r0 = wave * 8 + 2 * ip;
    const int r1 = r0 + 1;
    f32x4 acc[2][2][2];                  // [rr][jg][hM]
#pragma unroll
    for (int rr = 0; rr < 2; ++rr)
#pragma unroll
      for (int jg = 0; jg < 2; ++jg)
#pragma unroll
        for (int hM = 0; hM < 2; ++hM)
          acc[rr][jg][hM] = (f32x4){0.f, 0.f, 0.f, 0.f};

#pragma unroll
    for (int m = 0; m < 8; ++m) {
      const int doff = 32 * m + 8 * g;
      const uint4 ua0 = *(const uint4*)(xi + r0 * XPAD + doff);  // broadcast b128
      const uint4 ua1 = *(const uint4*)(xi + r1 * XPAD + doff);
#pragma unroll
      for (int jg = 0; jg < 2; ++jg) {
        const uint4 uc = *(const uint4*)(xj + (jg * 16 + m16) * XPAD + doff);
        const f16x2 c0 = bc2(uc.x), c1 = bc2(uc.y), c2 = bc2(uc.z), c3 = bc2(uc.w);
#pragma unroll
        for (int rr = 0; rr < 2; ++rr) {
          const uint4 ua = rr ? ua1 : ua0;
          const f16x2 a0 = bc2(ua.x), a1 = bc2(ua.y), a2 = bc2(ua.z), a3 = bc2(ua.w);
          const f16x2 p0 = a0 * c0, p1 = a1 * c1, p2 = a2 * c2, p3 = a3 * c3;
          const uint32_t s0 = __builtin_bit_cast(uint32_t, a0 - c0) & 0x7FFF7FFFu;
          const uint32_t s1 = __builtin_bit_cast(uint32_t, a1 - c1) & 0x7FFF7FFFu;
          const uint32_t s2 = __builtin_bit_cast(uint32_t, a2 - c2) & 0x7FFF7FFFu;
          const uint32_t s3 = __builtin_bit_cast(uint32_t, a3 - c3) & 0x7FFF7FFFu;
          uint4 be, bo;
          be.x = __builtin_bit_cast(uint32_t, p0); be.y = s0;
          be.z = __builtin_bit_cast(uint32_t, p1); be.w = s1;
          bo.x = __builtin_bit_cast(uint32_t, p2); bo.y = s2;
          bo.z = __builtin_bit_cast(uint32_t, p3); bo.w = s3;
          const halfx8 bE = bc8(be), bO = bc8(bo);
          acc[rr][jg][0] = __builtin_amdgcn_mfma_f32_16x16x32_f16(bc8(af[2 * m][0]),     bE, acc[rr][jg][0], 0, 0, 0);
          acc[rr][jg][1] = __builtin_amdgcn_mfma_f32_16x16x32_f16(bc8(af[2 * m][1]),     bE, acc[rr][jg][1], 0, 0, 0);
          acc[rr][jg][0] = __builtin_amdgcn_mfma_f32_16x16x32_f16(bc8(af[2 * m + 1][0]), bO, acc[rr][jg][0], 0, 0, 0);
          acc[rr][jg][1] = __builtin_amdgcn_mfma_f32_16x16x32_f16(bc8(af[2 * m + 1][1]), bO, acc[rr][jg][1], 0, 0, 0);
        }
      }
    }

    // D layout: c = 16*hM + (lane>>4)*4 + reg ; j = j0 + jg*16 + (lane&15)
#pragma unroll
    for (int rr = 0; rr < 2; ++rr) {
      const int i = i0 + (rr ? r1 : r0);
#pragma unroll
      for (int jg = 0; jg < 2; ++jg) {
        const int j = j0 + jg * 16 + m16;
        const float msk = (i < len && j < len) ? 1.f : 0.f;
        _Float16* hp = hws + ((size_t)(b * LL + i) * LL + j) * CH + g * 4;
#pragma unroll
        for (int hM = 0; hM < 2; ++hM) {
          const f32x4 a = acc[rr][jg][hM];
          uint2 st;
          st.x = pk16(fmaxf(a[0] + b1v[hM][0], 0.f) * msk,
                      fmaxf(a[1] + b1v[hM][1], 0.f) * msk);
          st.y = pk16(fmaxf(a[2] + b1v[hM][2], 0.f) * msk,
                      fmaxf(a[3] + b1v[hM][3], 0.f) * msk);
          *(uint2*)(hp + hM * 16) = st;
        }
      }
    }
  }
}

// ---------------------------------------------------------------------------
// Kernel B: out[b,i,j] = mask * ( sum_{di,dj,c} h[..]*W2[di,dj,c] + b2 )
// NEW: tiles entirely beyond protein_length[b] store zeros and exit.
// Halo staging guard now uses len (not LL): correct w.r.t. kernel A's skipped
// tiles AND drops ~40% of dead fetch traffic.
// ---------------------------------------------------------------------------
#define TROWS 22
#define TCOLS 38
#define TCPAD 39
__global__ __launch_bounds__(256, 4) void bepler_conv_kernel(
    const _Float16* __restrict__ hws, const uint32_t* __restrict__ w2p,
    const float* __restrict__ b2, const int* __restrict__ plen,
    float* __restrict__ out)
{
  __shared__ _Float16 htile[2 * TROWS * TCPAD * 8];   // 27,456 B

  const int tid = threadIdx.x;
  const int b   = blockIdx.z;
  const int i0  = blockIdx.y * 16;
  const int j0  = blockIdx.x * 32;
  const int l    = tid & 63;
  const int wave = tid >> 6;
  const int li = wave * 4 + (l & 3);   // output row in tile (bank-uniform map)
  const int pj = (l >> 2) & 15;        // output cols 2*pj, 2*pj+1

  const int len = plen[b];

  if (i0 >= len || j0 >= len) {        // block-uniform: whole out tile is zero
    const int i = i0 + li;
    const int j = j0 + 2 * pj;
    float2 z; z.x = 0.f; z.y = 0.f;
    *(float2*)(out + (size_t)(b * LL + i) * LL + j) = z;
    return;
  }

  float s0 = 0.f, s1 = 0.f;

  for (int ph = 0; ph < 2; ++ph) {     // channel phases: q = 2*ph, 2*ph+1
    for (int idx = tid; idx < TROWS * TCOLS; idx += 256) {
      const int row = idx / TCOLS, col = idx - row * TCOLS;
      const int gi = i0 - 3 + row, gj = j0 - 3 + col;
      uint4 v0 = make_uint4(0u, 0u, 0u, 0u), v1 = v0;
      if (gi >= 0 && gi < len && gj >= 0 && gj < len) {
        const uint4* src = (const uint4*)(hws + (((size_t)(b * LL + gi) * LL + gj) * CH + ph * 16));
        v0 = src[0];
        v1 = src[1];
      }
      *(uint4*)(htile + ((0 * TROWS + row) * TCPAD + col) * 8) = v0;
      *(uint4*)(htile + ((1 * TROWS + row) * TCPAD + col) * 8) = v1;
    }
    __syncthreads();

    f16x2 a0[8], a1[8];
#pragma unroll
    for (int t = 0; t < 8; ++t) { a0[t] = (f16x2){(_Float16)0, (_Float16)0};
                                  a1[t] = (f16x2){(_Float16)0, (_Float16)0}; }

    for (int di = 0; di < 7; ++di) {
      const int row = li + di;                  // 0..21
#pragma unroll
      for (int qq = 0; qq < 2; ++qq) {
        const _Float16* hrow = htile + ((qq * TROWS + row) * TCPAD) * 8;
        const uint32_t* wq = w2p + (di * 4 + 2 * ph + qq) * 28;  // uniform -> SGPR
#pragma unroll
        for (int p = 0; p < 8; ++p) {
          const uint4 u = *(const uint4*)(hrow + (2 * pj + p) * 8);
          const f16x2 h0 = bc2(u.x), h1 = bc2(u.y), h2 = bc2(u.z), h3 = bc2(u.w);
          if (p <= 6) {
            const uint32_t* w = wq + p * 4;
            a0[qq * 4 + 0] = __builtin_elementwise_fma(h0, bc2(w[0]), a0[qq * 4 + 0]);
            a0[qq * 4 + 1] = __builtin_elementwise_fma(h1, bc2(w[1]), a0[qq * 4 + 1]);
            a0[qq * 4 + 2] = __builtin_elementwise_fma(h2, bc2(w[2]), a0[qq * 4 + 2]);
            a0[qq * 4 + 3] = __builtin_elementwise_fma(h3, bc2(w[3]), a0[qq * 4 + 3]);
          }
          if (p >= 1) {
            const uint32_t* w = wq + (p - 1) * 4;
            a1[qq * 4 + 0] = __builtin_elementwise_fma(h0, bc2(w[0]), a1[qq * 4 + 0]);
            a1[qq * 4 + 1] = __builtin_elementwise_fma(h1, bc2(w[1]), a1[qq * 4 + 1]);
            a1[qq * 4 + 2] = __builtin_elementwise_fma(h2, bc2(w[2]), a1[qq * 4 + 2]);
            a1[qq * 4 + 3] = __builtin_elementwise_fma(h3, bc2(w[3]), a1[qq * 4 + 3]);
          }
        }
      }
    }

#pragma unroll
    for (int t = 0; t < 8; ++t) {
      s0 += (float)a0[t].x + (float)a0[t].y;
      s1 += (float)a1[t].x + (float)a1[t].y;
    }
    __syncthreads();   // before next phase overwrites htile
  }

  const int i = i0 + li;
  const int j = j0 + 2 * pj;
  const float bias = b2[0];
  float2 o;
  o.x = (i < len && (j + 0) < len) ? s0 + bias : 0.f;
  o.y = (i < len && (j + 1) < len) ? s1 + bias : 0.f;
  *(float2*)(out + (size_t)(b * LL + i) * LL + j) = o;
}

extern "C" void kernel_launch(void* const* d_in, const int* in_sizes, int n_in,
                              void* d_out, int out_size, void* d_ws, size_t ws_size,
                              hipStream_t stream) {
  const float* x   = (const float*)d_in[0];
  const int*   pl  = (const int*)d_in[1];
  const float* W1  = (const float*)d_in[2];
  const float* b1  = (const float*)d_in[3];
  const float* W2  = (const float*)d_in[4];
  const float* b2  = (const float*)d_in[5];
  float* out = (float*)d_out;

  _Float16* hws = (_Float16*)d_ws;                            // 33,554,432 B
  _Float16* w1p = (_Float16*)((char*)d_ws + 33554432);        // 32,768 B
  uint32_t* w2p = (uint32_t*)((char*)d_ws + 33587200);        // 3,136 B
  _Float16* xf  = (_Float16*)((char*)d_ws + 33591296);        // 1,048,576 B

  bepler_pack<<<dim3(321), dim3(256), 0, stream>>>(x, W1, W2, xf, w1p, w2p);
  dim3 gA(8, 8, 8);    // (j-tile/32, i-tile/32, b)
  bepler_h_kernel<<<gA, dim3(256), 0, stream>>>(xf, pl, (const uint4*)w1p, b1, hws);
  dim3 gB(8, 16, 8);   // (j-tile/32, i-tile/16, b)
  bepler_conv_kernel<<<gB, dim3(256), 0, stream>>>(hws, w2p, b2, pl, out);
}